// Round 8
// baseline (54.597 us; speedup 1.0000x reference)
//
#include <hip/hip_runtime.h>

// PointNet++ grouping: ball query (radius 0.2, nsample 64) + gather + concat.
// Shapes fixed by setup_inputs(): B=4, N=16384, npoint=2048, C=64.
// out[b][j][c][s]: c in [0,3) = xyz[idx]-new_xyz, c in [3,67) = features[c-3][idx].
//
// Structure (round 8):
//   Kernel A: transpose and ball-query run CONCURRENTLY as block roles,
//     XCD-partitioned (XCD pair p owns batch p; per XCD: 128 transpose
//     blocks + 256 query blocks). Query writes idxbuf + 3 xyz channels.
//     The ~6us transpose hides under the ~9us query instead of serializing.
//   Kernel B: pure cooperative gather: 1 idx load + 16 dwordx4 row loads +
//     conflict-free LDS lane transpose + 16 x 1KB NT dwordx4 stores per
//     wave. Nothing ahead of the store stream -> near fill-rate writes.

#define BB 4
#define NN 16384
#define NP 2048
#define CC 64
#define NS 64
#define CH (3 + CC)
#define NCHUNK (NN / 256)   // 64 chunks of 256 points
#define ST 65               // LDS tile row stride (floats); conflict-free

typedef float f32x4 __attribute__((ext_vector_type(4)));

// ---------- Kernel A: transpose role + query role ----------
__global__ __launch_bounds__(256) void pn2_prep_kernel(
    const float* __restrict__ xyz,       // (B, N, 3)
    const float* __restrict__ new_xyz,   // (B, NP, 3)
    const float* __restrict__ features,  // (B, C, N)
    float* __restrict__ ft,              // ws: (B, N, C)
    int* __restrict__ idxbuf,            // ws: (B*NP, NS)
    float* __restrict__ out)             // (B, NP, CH, NS)
{
    __shared__ float tile[CC][65];
    __shared__ int sidx[4][NS];

    const int g = blockIdx.x;            // 3072 blocks
    const int xcd = g & 7;
    const int r = g >> 3;                // 0..383 within XCD
    const int b = xcd >> 1;              // batch owned by this XCD pair
    const int h = xcd & 1;               // which half of the pair

    if (r < 128) {
        // ---- transpose role: tile t of batch b ----
        const int t = h * 128 + r;       // 0..255
        const int n0 = t << 6;
        const int col = threadIdx.x & 63;
        const int r4  = threadIdx.x >> 6;
        const float* src = features + (size_t)b * CC * NN;
#pragma unroll
        for (int i = 0; i < 16; ++i) {
            const int c = r4 + i * 4;
            tile[c][col] = __builtin_nontemporal_load(&src[(size_t)c * NN + n0 + col]);
        }
        __syncthreads();
        float* dst = ft + ((size_t)b * NN + n0) * CC;
#pragma unroll
        for (int i = 0; i < 16; ++i) {
            const int n = r4 + i * 4;
            dst[(size_t)n * CC + col] = tile[col][n];    // coalesced along c
        }
        return;
    }

    // ---- query role: one wave per center ----
    const int lane = threadIdx.x & 63;
    const int wave = threadIdx.x >> 6;
    const int grp = h * 256 + (r - 128);         // 0..511
    const int j = grp * 4 + wave;                // 0..2047 within batch
    const int center = b * NP + j;

    const float r2 = 0.04f;                      // f32(0.2*0.2)
    const float* q = new_xyz + ((size_t)b * NP + j) * 3;
    const float cx = q[0], cy = q[1], cz = q[2];

    const float* xb = xyz + (size_t)b * NN * 3;
    const float4* x4 = (const float4*)xb;
    int* widx = sidx[wave];

    const int base = 3 * lane;
    const unsigned long long low = (1ull << lane) - 1ull;
    int found = 0;
    int it = 0;
    float4 A = x4[base], Bv = x4[base + 1], Cv = x4[base + 2];

    while (true) {
        const int nit = (it + 1 < NCHUNK) ? it + 1 : it;
        const size_t nb = (size_t)nit * 192 + base;
        float4 nA = x4[nb], nB = x4[nb + 1], nC = x4[nb + 2];

        const int n0 = it * 256 + 4 * lane;
        const float px[4] = {A.x, A.w, Bv.z, Cv.y};
        const float py[4] = {A.y, Bv.x, Bv.w, Cv.z};
        const float pz[4] = {A.z, Bv.y, Cv.x, Cv.w};
        bool in[4];
        unsigned long long m[4];
#pragma unroll
        for (int k = 0; k < 4; ++k) {
            const float dx = px[k] - cx;
            const float dy = py[k] - cy;
            const float dz = pz[k] - cz;
            // match numpy: plain f32 mul/add, left-to-right, NO fma contraction
            const float d2 = __fadd_rn(__fadd_rn(__fmul_rn(dx, dx), __fmul_rn(dy, dy)),
                                       __fmul_rn(dz, dz));
            in[k] = d2 < r2;
            m[k] = __ballot(in[k]);
        }
        int pos = found
                + (int)__popcll(m[0] & low) + (int)__popcll(m[1] & low)
                + (int)__popcll(m[2] & low) + (int)__popcll(m[3] & low);
#pragma unroll
        for (int k = 0; k < 4; ++k) {
            if (in[k]) {
                if (pos < NS) widx[pos] = n0 + k;
                ++pos;
            }
        }
        found += (int)(__popcll(m[0]) + __popcll(m[1])
                     + __popcll(m[2]) + __popcll(m[3]));     // wave-uniform
        if (found >= NS || it == NCHUNK - 1) break;          // uniform branch
        A = nA; Bv = nB; Cv = nC; ++it;
    }

    // ref fill semantics: pad with first found idx, 0 if none found
    int myidx = 0;
    if (found > 0) {
        const int first = widx[0];
        myidx = (lane < found) ? widx[lane] : first;
    }
    idxbuf[(size_t)center * NS + lane] = myidx;              // coalesced

    // xyz channels (lane = sample slot; 256B-coalesced NT stores)
    const float* pp = xb + (size_t)myidx * 3;
    float* ob = out + (size_t)center * CH * NS;
    __builtin_nontemporal_store(pp[0] - cx, ob + 0 * NS + lane);
    __builtin_nontemporal_store(pp[1] - cy, ob + 1 * NS + lane);
    __builtin_nontemporal_store(pp[2] - cz, ob + 2 * NS + lane);
}

// ---------- Kernel B: pure cooperative gather ----------
__global__ __launch_bounds__(256, 4) void pn2_gather_kernel(
    const float* __restrict__ ft,        // ws: (B, N, C)
    const int* __restrict__ idxbuf,      // ws: (B*NP, NS)
    float* __restrict__ out)             // (B, NP, CH, NS)
{
    __shared__ int sidx[4][NS];
    __shared__ float stile[4][32 * ST];  // 8.3KB/wave transpose tile

    const int g = blockIdx.x;            // 2048 blocks
    const int xcd = g & 7;
    const int r = g >> 3;                // 0..255
    const int b = xcd >> 1;              // same batch pinning as kernel A
    const int h = xcd & 1;

    const int lane = threadIdx.x & 63;
    const int wave = threadIdx.x >> 6;
    const int j = (h * 256 + r) * 4 + wave;      // 0..2047
    const int center = b * NP + j;

    int* widx = sidx[wave];
    widx[lane] = idxbuf[(size_t)center * NS + lane];   // coalesced dword
    // wave-internal LDS dependency; compiler inserts the lgkmcnt wait

    const float* ftb = ft + (size_t)b * NN * CC;
    float* tw = stile[wave];
    float* ob = out + (size_t)center * CH * NS;
    const int sub  = lane & 15;   // 16B chunk within a row
    const int rsub = lane >> 4;   // which of 4 rows this instr covers
    const int sq   = lane & 7;    // sample quad within half
    const int cc8  = lane >> 3;   // channel offset within group of 8

#pragma unroll
    for (int hh = 0; hh < 2; ++hh) {
        int ridx[8];
#pragma unroll
        for (int i = 0; i < 8; ++i) ridx[i] = widx[32 * hh + 4 * i + rsub];
        float4 v[8];
#pragma unroll
        for (int i = 0; i < 8; ++i)   // 8 dwordx4, contiguous 256B lane groups
            v[i] = *(const float4*)(ftb + (size_t)ridx[i] * CC + 4 * sub);
#pragma unroll
        for (int i = 0; i < 8; ++i) { // tile[sample][channel], <=2-way banks
            float* tr = tw + (4 * i + rsub) * ST + 4 * sub;
            tr[0] = v[i].x; tr[1] = v[i].y; tr[2] = v[i].z; tr[3] = v[i].w;
        }
#pragma unroll
        for (int t = 0; t < 8; ++t) { // 8 dwordx4 NT stores per half
            const int c = 8 * t + cc8;
            f32x4 u;
            u.x = tw[(4 * sq + 0) * ST + c];
            u.y = tw[(4 * sq + 1) * ST + c];
            u.z = tw[(4 * sq + 2) * ST + c];
            u.w = tw[(4 * sq + 3) * ST + c];
            float* o = ob + (size_t)(3 + c) * NS + 32 * hh + 4 * sq;  // 16B aligned
            __builtin_nontemporal_store(u, (f32x4*)o);
        }
    }
}

// ---------- Fallback (ws too small): round-1 direct-gather kernel ----------
__global__ __launch_bounds__(256, 4) void pn2_group_kernel(
    const float* __restrict__ xyz, const float* __restrict__ new_xyz,
    const float* __restrict__ features, float* __restrict__ out)
{
    __shared__ int sidx[4][NS];
    const int lane = threadIdx.x & 63;
    const int wave = threadIdx.x >> 6;
    const int center = blockIdx.x * 4 + wave;
    const int b = center >> 11;
    const int j = center & (NP - 1);
    const float r2 = 0.04f;
    const float* q = new_xyz + ((size_t)b * NP + j) * 3;
    const float cx = q[0], cy = q[1], cz = q[2];
    int* widx = sidx[wave];
    int found = 0;
    for (int it = 0; it < NN / 64; ++it) {
        const int n = it * 64 + lane;
        const float* p = xyz + ((size_t)b * NN + n) * 3;
        const float dx = p[0] - cx, dy = p[1] - cy, dz = p[2] - cz;
        const float d2 = __fadd_rn(__fadd_rn(__fmul_rn(dx, dx), __fmul_rn(dy, dy)),
                                   __fmul_rn(dz, dz));
        const bool within = d2 < r2;
        const unsigned long long mask = __ballot(within);
        const int pos = found + (int)__popcll(mask & ((1ull << lane) - 1ull));
        if (within && pos < NS) widx[pos] = n;
        found += (int)__popcll(mask);
        if (found >= NS) break;
    }
    int myidx = 0;
    if (found > 0) {
        const int first = widx[0];
        myidx = (lane < found) ? widx[lane] : first;
    }
    const float* pp = xyz + ((size_t)b * NN + myidx) * 3;
    float* ob = out + (((size_t)b * NP + j) * (size_t)CH) * NS + lane;
    ob[0 * NS] = pp[0] - cx;
    ob[1 * NS] = pp[1] - cy;
    ob[2 * NS] = pp[2] - cz;
    const float* fb = features + (size_t)b * CC * NN + myidx;
#pragma unroll 8
    for (int c = 0; c < CC; ++c) ob[(size_t)(3 + c) * NS] = fb[(size_t)c * NN];
}

extern "C" void kernel_launch(void* const* d_in, const int* in_sizes, int n_in,
                              void* d_out, int out_size, void* d_ws, size_t ws_size,
                              hipStream_t stream) {
    const float* xyz      = (const float*)d_in[0];
    const float* new_xyz  = (const float*)d_in[1];
    const float* features = (const float*)d_in[2];
    float* out = (float*)d_out;

    const size_t ft_bytes  = (size_t)BB * NN * CC * sizeof(float);  // 16.8 MB
    const size_t idx_bytes = (size_t)BB * NP * NS * sizeof(int);    //  2.1 MB

    if (ws_size >= ft_bytes + idx_bytes) {
        float* ft   = (float*)d_ws;
        int* idxbuf = (int*)((char*)d_ws + ft_bytes);
        pn2_prep_kernel<<<3072, 256, 0, stream>>>(xyz, new_xyz, features,
                                                  ft, idxbuf, out);
        pn2_gather_kernel<<<2048, 256, 0, stream>>>(ft, idxbuf, out);
    } else {
        pn2_group_kernel<<<BB * NP / 4, 256, 0, stream>>>(xyz, new_xyz, features, out);
    }
}